// Round 11
// baseline (182.062 us; speedup 1.0000x reference)
//
#include <hip/hip_runtime.h>
#include <hip/hip_bf16.h>
#include <math.h>

#define B_     16
#define C_     256
#define H_     56
#define W_     56
#define HEADS_ 4
#define CPER_  64
#define R_     16
#define HW_    (H_*W_)      // 3136
#define HP_    58           // halo-padded dim
#define HWP_   (HP_*HP_)    // 3364
#define BN_EPS_ 1e-5f

typedef short bf16x8 __attribute__((ext_vector_type(8)));
typedef float f32x4  __attribute__((ext_vector_type(4)));

__device__ inline unsigned short f2bf(float f) {
    unsigned int u = __builtin_bit_cast(unsigned int, f);
    u += 0x7fffu + ((u >> 16) & 1u);          // RNE (finite inputs only)
    return (unsigned short)(u >> 16);
}

// ---------------- K0: BN+ReLU+mean per (b,c) plane, 4 planes/block, 4-deep MLP ---------
__global__ __launch_bounds__(256) void k_pool(
    const float* __restrict__ x,
    const float* __restrict__ gamma, const float* __restrict__ beta,
    const float* __restrict__ mean,  const float* __restrict__ var,
    float* __restrict__ xavg)
{
    int wv = threadIdx.x >> 6, ln = threadIdx.x & 63;
    int plane = blockIdx.x * 4 + wv;          // b*256 + c
    int c = plane & (C_ - 1);
    float s = gamma[c] * rsqrtf(var[c] + BN_EPS_);
    float t = fmaf(-mean[c], s, beta[c]);
    const float4* xp = (const float4*)(x + (size_t)plane * HW_);
    float s0 = 0.f, s1 = 0.f, s2 = 0.f, s3 = 0.f;
    #pragma unroll
    for (int i = 0; i < 3; ++i) {             // 784 = 12*64 + 16; 4 loads in flight
        float4 a = xp[ln + (i * 4 + 0) * 64];
        float4 b2 = xp[ln + (i * 4 + 1) * 64];
        float4 c2 = xp[ln + (i * 4 + 2) * 64];
        float4 d = xp[ln + (i * 4 + 3) * 64];
        s0 += fmaxf(fmaf(a.x, s, t), 0.f) + fmaxf(fmaf(a.y, s, t), 0.f)
            + fmaxf(fmaf(a.z, s, t), 0.f) + fmaxf(fmaf(a.w, s, t), 0.f);
        s1 += fmaxf(fmaf(b2.x, s, t), 0.f) + fmaxf(fmaf(b2.y, s, t), 0.f)
            + fmaxf(fmaf(b2.z, s, t), 0.f) + fmaxf(fmaf(b2.w, s, t), 0.f);
        s2 += fmaxf(fmaf(c2.x, s, t), 0.f) + fmaxf(fmaf(c2.y, s, t), 0.f)
            + fmaxf(fmaf(c2.z, s, t), 0.f) + fmaxf(fmaf(c2.w, s, t), 0.f);
        s3 += fmaxf(fmaf(d.x, s, t), 0.f) + fmaxf(fmaf(d.y, s, t), 0.f)
            + fmaxf(fmaf(d.z, s, t), 0.f) + fmaxf(fmaf(d.w, s, t), 0.f);
    }
    if (ln < 16) {
        float4 e = xp[768 + ln];
        s0 += fmaxf(fmaf(e.x, s, t), 0.f) + fmaxf(fmaf(e.y, s, t), 0.f)
            + fmaxf(fmaf(e.z, s, t), 0.f) + fmaxf(fmaf(e.w, s, t), 0.f);
    }
    float sum = (s0 + s1) + (s2 + s3);
    for (int off = 32; off; off >>= 1) sum += __shfl_down(sum, off, 64);
    if (ln == 0) xavg[plane] = sum * (1.f / HW_);
}

// ---------------- K2: SE gate + threshold + lasso + weight gather (j-sliced, grid.y=4) -
// Deterministic ballot/prefix compaction (ascending channel) -- identical list in every
// redundant block regardless of scheduling.
__global__ __launch_bounds__(256) void k_se_wg(
    const float* __restrict__ xavg,
    const float* __restrict__ fc1, const float* __restrict__ fc2,
    const float* __restrict__ fc2b, const int* __restrict__ kptr,
    const float* __restrict__ convw,
    int* __restrict__ aidx64, float* __restrict__ lasso,
    short* __restrict__ Wc)
{
    int hb = blockIdx.x;              // h*B + b
    int j0 = blockIdx.y * 16;         // this block's j-slice
    int h = hb / B_, b = hb - h * B_;
    int tid = threadIdx.x;            // = channel c

    __shared__ float sav[C_], sy1[R_], smask[C_], sred[4], sthr;
    __shared__ int s_ord[C_];
    __shared__ unsigned long long sbal[4];
    __shared__ int s_act[64];
    __shared__ float s_mv[64];
    __shared__ short sO[9 * 1024];    // 18 KB staged weight slice

    sav[tid] = xavg[b * C_ + tid];
    __syncthreads();

    if (tid < R_) {
        const float* w = fc1 + (size_t)(h * R_ + tid) * C_;
        float acc = 0.f;
        for (int c2 = 0; c2 < C_; ++c2) acc = fmaf(sav[c2], w[c2], acc);
        sy1[tid] = fmaxf(acc, 0.f);
    }
    __syncthreads();

    const float* w2 = fc2 + (size_t)(h * C_ + tid) * R_;
    float acc = fc2b[h * C_ + tid];
    for (int r = 0; r < R_; ++r) acc = fmaf(sy1[r], w2[r], acc);
    float m = fmaxf(acc, 0.f);
    smask[tid] = m;
    __syncthreads();

    int lane = tid & 63, wv = tid >> 6;
    float ls = m;
    for (int off = 32; off > 0; off >>= 1) ls += __shfl_down(ls, off, 64);
    if (lane == 0) sred[wv] = ls;

    int cl = 0, ce = 0;
    for (int j = 0; j < C_; ++j) {
        float vj = smask[j];
        cl += (vj < m);
        ce += (vj == m);
    }
    if (tid == 0) sthr = -1e30f;
    __syncthreads();
    int k = kptr[0];
    if (k > 0 && cl <= k - 1 && (k - 1) < cl + ce) sthr = m;
    __syncthreads();

    float thr = sthr;
    float mc = (m <= thr) ? 0.f : m;

    // deterministic order-preserving compaction (ascending channel)
    bool active = (mc != 0.f);
    unsigned long long bal = __ballot(active);
    if (lane == 0) sbal[wv] = bal;
    __syncthreads();
    int base = 0, total = 0;
    #pragma unroll
    for (int w = 0; w < 4; ++w) {
        int pc = __popcll(sbal[w]);
        if (w < wv) base += pc;
        total += pc;
    }
    if (active)
        s_ord[base + __popcll(bal & ((1ull << lane) - 1ull))] = tid;
    __syncthreads();

    if (tid < 64) {
        int a = (tid < total) ? s_ord[tid] : 0;  // zero-padded (padded weights are 0)
        s_act[tid] = a;
        s_mv[tid]  = (tid < total) ? smask[a] : 0.f;
        if (blockIdx.y == 0) aidx64[hb * 64 + tid] = a;
    }
    if (tid == 0 && blockIdx.y == 0)
        atomicAdd(lasso, (sred[0] + sred[1] + sred[2] + sred[3]) * (1.f / (B_ * C_)));
    __syncthreads();

    // ---- weight gather for j in [j0, j0+16): 36B granules, rotated stage, coalesced out
    const float* wsrc = convw + (size_t)h * CPER_ * C_ * 9;
    for (int it = 0; it < 4; ++it) {
        int e = it * 256 + tid;               // e < 1024 = 16j x 64cp
        int cp = e & 63, jj = e >> 6;
        int j = j0 + jj;
        const float* wp = wsrc + ((size_t)j * C_ + s_act[cp]) * 9;
        float mv = s_mv[cp];
        int slot = (cp + 8 * (j & 7)) & 63;   // pre-rotate for k_conv LDS bank spread
        #pragma unroll
        for (int t = 0; t < 9; ++t)
            sO[t * 1024 + jj * 64 + slot] = (short)f2bf(wp[t] * mv);
    }
    __syncthreads();
    short* wdst = Wc + (size_t)hb * 9 * 4096 + j0 * 64;
    for (int it = 0; it < 5; ++it) {          // 1152 bf16x8 vecs
        int v = it * 256 + tid;
        if (v < 1152) {
            int t = v >> 7, r8 = v & 127;     // 128 vec8 per tap slice
            *(bf16x8*)&wdst[t * 4096 + r8 * 8] = *(const bf16x8*)&sO[t * 1024 + r8 * 8];
        }
    }
}

// ---------------- K1: BN+ReLU+bf16 + per-head compaction -> HALO-PADDED xc -------------
// xc layout [hb][(y+1)*58+(x+1)][64ch]: 1-px zero border so k_conv's B-loads are
// UNCONDITIONAL. Interior written at +1 offsets; x-halo (px 0,57) zeroed per row;
// y-halo rows (0,57) zeroed by the y==0 / y==55 blocks. Halo must be re-zeroed every
// iteration (harness poisons the workspace). Phase-2 stores upgraded to 8B uint2.
__global__ __launch_bounds__(256) void k_bnc(
    const float* __restrict__ x,
    const float* __restrict__ gamma, const float* __restrict__ beta,
    const float* __restrict__ mean,  const float* __restrict__ var,
    const int* __restrict__ aidx64, short* __restrict__ xc)
{
    int y = blockIdx.x, b = blockIdx.y;
    int tid = threadIdx.x;
    __shared__ unsigned short T[W_ * 258];    // [px][c], +2 pad breaks stride-256 conflicts
    __shared__ float ss[C_], st[C_];
    __shared__ short sact[256];               // [h][64]

    {
        float s = gamma[tid] * rsqrtf(var[tid] + BN_EPS_);
        ss[tid] = s;
        st[tid] = fmaf(-mean[tid], s, beta[tid]);
        int h = tid >> 6, cp = tid & 63;
        sact[tid] = (short)aidx64[(h * B_ + b) * 64 + cp];
    }
    __syncthreads();

    const float* xrow = x + (size_t)b * C_ * HW_ + y * W_;
    for (int i = tid; i < C_ * 14; i += 256) {    // 14 float4 per channel row, coalesced
        int c = i / 14, f = i - c * 14;
        float4 v = *(const float4*)(xrow + (size_t)c * HW_ + f * 4);
        float s = ss[c], t = st[c];
        int xb = f * 4;
        T[(xb + 0) * 258 + c] = f2bf(fmaxf(fmaf(v.x, s, t), 0.f));
        T[(xb + 1) * 258 + c] = f2bf(fmaxf(fmaf(v.y, s, t), 0.f));
        T[(xb + 2) * 258 + c] = f2bf(fmaxf(fmaf(v.z, s, t), 0.f));
        T[(xb + 3) * 258 + c] = f2bf(fmaxf(fmaf(v.w, s, t), 0.f));
    }
    __syncthreads();

    uint2 zz; zz.x = 0u; zz.y = 0u;
    uint2* ob = (uint2*)xc;                   // 16 uint2 per pixel (64 ch)
    #pragma unroll
    for (int h = 0; h < HEADS_; ++h) {
        size_t bh = ((size_t)(h * B_ + b) * HWP_ + (size_t)(y + 1) * HP_) * 16;
        for (int i = tid; i < W_ * 16; i += 256) {    // 896 items
            int px = i >> 4, d = i & 15;
            int c0 = 4 * d;
            unsigned int a0 = T[px * 258 + sact[h * 64 + c0]];
            unsigned int a1 = T[px * 258 + sact[h * 64 + c0 + 1]];
            unsigned int a2 = T[px * 258 + sact[h * 64 + c0 + 2]];
            unsigned int a3 = T[px * 258 + sact[h * 64 + c0 + 3]];
            uint2 u; u.x = a0 | (a1 << 16); u.y = a2 | (a3 << 16);
            ob[bh + (size_t)(px + 1) * 16 + d] = u;
        }
    }
    // x-halo: px 0 and 57 of this row, all heads (128 uint2)
    if (tid < 128) {
        int h = tid >> 5, side = (tid >> 4) & 1, d = tid & 15;
        ob[((size_t)(h * B_ + b) * HWP_ + (size_t)(y + 1) * HP_ + side * 57) * 16 + d] = zz;
    }
    // y-halo: full rows 0 / 57 by the edge blocks
    if (y == 0 || y == H_ - 1) {
        int row = (y == 0) ? 0 : HP_ - 1;
        for (int i = tid; i < HEADS_ * HP_ * 16; i += 256) {   // 3712 items
            int h = i / (HP_ * 16); int rem = i - h * (HP_ * 16);
            ob[((size_t)(h * B_ + b) * HWP_ + (size_t)row * HP_) * 16 + rem] = zz;
        }
    }
}

// ---------------- K3: implicit-GEMM conv, halo-padded input, UNCONDITIONAL B-loads -----
// R10 structure (single dispatch, 896 blocks, manual 2-deep pipeline, one barrier) but
// every B-load is now branch-free with compile-time per-cluster offsets: no bounds
// VALU, no exec-mask cndmask, clean vmcnt accounting.
__global__ __launch_bounds__(256, 2) void k_conv(
    const short* __restrict__ xc, const short* __restrict__ Wc,
    float* __restrict__ out)
{
    int g = blockIdx.x;
    int vx = g & 7, r = g >> 3;               // XCD-local hb window (Wc/xc L2-resident)
    int hb = vx * 8 + r / 14;
    int band = r - (r / 14) * 14;
    int h = hb >> 4, b = hb & 15;
    int tid = threadIdx.x, lane = tid & 63, wv = tid >> 6;
    int m = lane & 15, q = lane >> 4;
    int yrow = band * 4 + wv;
    int arot = q * 8 + 8 * (m & 7);           // A-frag slot rotation (add c0, &63)

    __shared__ short sW[9 * 4096];            // 73.7 KB, all taps

    const short* Wh = Wc + (size_t)hb * 9 * 4096;
    // per-lane base at (yrow+1, m+1), ch q*8; cluster deltas are compile-time
    const short* xb = xc + (size_t)hb * HWP_ * 64
                    + ((size_t)(yrow + 1) * HP_ + (m + 1)) * 64 + q * 8;

    bf16x8 bFb[3][4];                         // B rotating buffer (48 VGPR)
    bf16x8 aFb[2][4];                         // A rotating buffer (32 VGPR)

#define LOADB_(kk) { \
        const int t_ = (kk) >> 1, c0_ = ((kk) & 1) * 32; \
        const int dy_ = t_ / 3 - 1, dx_ = t_ % 3 - 1; \
        _Pragma("unroll") \
        for (int xt_ = 0; xt_ < 4; ++xt_) \
            bFb[(kk) % 3][xt_] = *(const bf16x8*)(xb + \
                (dy_ * HP_ + dx_ + xt_ * 16) * 64 + c0_); \
        }

#define LOADA_(kk) { \
        const int t_ = (kk) >> 1, c0_ = ((kk) & 1) * 32; \
        const short* sWc_ = sW + t_ * 4096; \
        _Pragma("unroll") \
        for (int jt_ = 0; jt_ < 4; ++jt_) \
            aFb[(kk) % 2][jt_] = *(const bf16x8*)&sWc_[(jt_ * 16 + m) * 64 + ((c0_ + arot) & 63)]; \
        }

    LOADB_(0);                                // hide under staging + barrier
    LOADB_(1);

    #pragma unroll
    for (int it = 0; it < 18; ++it) {         // stage all 9 taps, 16B/lane coalesced
        int e = it * 256 + tid;
        *(bf16x8*)&sW[e * 8] = *(const bf16x8*)(Wh + e * 8);
    }
    __syncthreads();

    f32x4 acc[4][4];                          // [jt][xt], 64 AGPR
    #pragma unroll
    for (int i = 0; i < 4; ++i)
        #pragma unroll
        for (int j = 0; j < 4; ++j)
            #pragma unroll
            for (int rr = 0; rr < 4; ++rr) acc[i][j][rr] = 0.f;

    LOADA_(0);

    #pragma unroll
    for (int k = 0; k < 18; ++k) {            // 18 clusters = 9 taps x 2 c0-halves
        if (k + 2 < 18) LOADB_(k + 2);        // issue 2 clusters ahead (WAR-pinned)
        if (k + 1 < 18) LOADA_(k + 1);        // LDS prefetch 1 cluster ahead
        #pragma unroll
        for (int jt = 0; jt < 4; ++jt)
            #pragma unroll
            for (int xt = 0; xt < 4; ++xt)
                acc[jt][xt] = __builtin_amdgcn_mfma_f32_16x16x32_bf16(
                    aFb[k % 2][jt], bFb[k % 3][xt], acc[jt][xt], 0, 0, 0);
    }
#undef LOADB_
#undef LOADA_

    #pragma unroll
    for (int xt = 0; xt < 4; ++xt) {
        int xx = xt * 16 + m;
        if (xx < W_) {
            #pragma unroll
            for (int jt = 0; jt < 4; ++jt)
                #pragma unroll
                for (int rr = 0; rr < 4; ++rr) {
                    int j = jt * 16 + q * 4 + rr;         // D: row = quad*4 + reg
                    int oc = j * HEADS_ + h;              // head interleave
                    out[(((size_t)b * C_ + oc) * H_ + yrow) * W_ + xx] = acc[jt][xt][rr];
                }
        }
    }
}

// ---------------- launch ----------------------------------------------------------------
extern "C" void kernel_launch(void* const* d_in, const int* in_sizes, int n_in,
                              void* d_out, int out_size, void* d_ws, size_t ws_size,
                              hipStream_t stream)
{
    const float* x     = (const float*)d_in[0];
    const float* gamma = (const float*)d_in[1];
    const float* beta  = (const float*)d_in[2];
    const float* mean  = (const float*)d_in[3];
    const float* var   = (const float*)d_in[4];
    const float* fc1   = (const float*)d_in[5];
    const float* fc2   = (const float*)d_in[6];
    const float* fc2b  = (const float*)d_in[7];
    const float* convw = (const float*)d_in[8];
    const int*   kptr  = (const int*)d_in[9];

    float* out   = (float*)d_out;
    float* lasso = out + (size_t)B_ * C_ * HW_;

    char* ws = (char*)d_ws;
    size_t off = 0;
    short* xc    = (short*)(ws + off); off += (size_t)HEADS_ * B_ * HWP_ * 64 * 2;  // 27.6 MB
    off = (off + 255) & ~(size_t)255;
    float* xavg  = (float*)(ws + off); off += (size_t)B_ * C_ * 4;
    int*   aidx64= (int*)  (ws + off); off += (size_t)HEADS_ * B_ * 64 * 4;
    off = (off + 255) & ~(size_t)255;
    short* Wc    = (short*)(ws + off); off += (size_t)HEADS_ * B_ * 9 * CPER_ * 64 * 2; // 4.72 MB

    hipMemsetAsync(lasso, 0, 4, stream);

    k_pool<<<B_ * C_ / 4, 256, 0, stream>>>(x, gamma, beta, mean, var, xavg);
    k_se_wg<<<dim3(HEADS_ * B_, 4), 256, 0, stream>>>(xavg, fc1, fc2, fc2b, kptr, convw,
                                                      aidx64, lasso, Wc);
    k_bnc<<<dim3(H_, B_), 256, 0, stream>>>(x, gamma, beta, mean, var, aidx64, xc);
    k_conv<<<HEADS_ * B_ * (H_ / 4), 256, 0, stream>>>(xc, Wc, out);
}